// Round 5
// baseline (287.436 us; speedup 1.0000x reference)
//
#include <hip/hip_runtime.h>

// Weighted MSE loss:
//   bin i s.t. edge[i] < t <= edge[i+1]  -> weight[i]; outside -> 0
//   loss = sum(w * (p - t)^2) / sum(weights)
// R4: two-stage reduction. R1/R2 both ~110us regardless of ILP -> theory:
// 2048 same-address atomicAdds serialize (~30-50ns each) as all blocks finish
// together = ~60-100us tail. Stage 1 streams + writes per-block partials to
// d_ws (no atomics); stage 2 (1 block) reduces 2048 partials -> out[0].

__device__ __forceinline__ float wmse_elem(float p, float t,
                                           float e0, float e1, float e2,
                                           float e3, float e4, float e5,
                                           float w0, float w1, float w2,
                                           float w3, float w4) {
    float w = 0.0f;
    w = (t > e0 && t <= e1) ? w0 : w;
    w = (t > e1 && t <= e2) ? w1 : w;
    w = (t > e2 && t <= e3) ? w2 : w;
    w = (t > e3 && t <= e4) ? w3 : w;
    w = (t > e4 && t <= e5) ? w4 : w;
    float d = p - t;
    return w * d * d;
}

#define WMSE4(p, t) (                                                          \
    wmse_elem((p).x, (t).x, e0, e1, e2, e3, e4, e5, w0, w1, w2, w3, w4) +      \
    wmse_elem((p).y, (t).y, e0, e1, e2, e3, e4, e5, w0, w1, w2, w3, w4) +      \
    wmse_elem((p).z, (t).z, e0, e1, e2, e3, e4, e5, w0, w1, w2, w3, w4) +      \
    wmse_elem((p).w, (t).w, e0, e1, e2, e3, e4, e5, w0, w1, w2, w3, w4))

__global__ __launch_bounds__(256) void WeightedMSELoss_60335700574782_kernel(
    const float* __restrict__ pred, const float* __restrict__ targ,
    const float* __restrict__ edge, const float* __restrict__ weights,
    float* __restrict__ partial, long long n) {
    const float e0 = edge[0], e1 = edge[1], e2 = edge[2];
    const float e3 = edge[3], e4 = edge[4], e5 = edge[5];
    const float w0 = weights[0], w1 = weights[1], w2 = weights[2];
    const float w3 = weights[3], w4 = weights[4];

    const int tid = blockIdx.x * blockDim.x + threadIdx.x;
    const int stride = gridDim.x * blockDim.x;        // 524288 at grid=2048
    const long long n4 = n >> 2;                      // float4 chunks

    const float4* __restrict__ p4 = (const float4*)pred;
    const float4* __restrict__ t4 = (const float4*)targ;

    const int iters = (int)(n4 / (4LL * stride));
    const long long n4_main = (long long)iters * 4LL * stride;

    float acc0 = 0.0f, acc1 = 0.0f, acc2 = 0.0f, acc3 = 0.0f;
    int i = tid;
    for (int k = 0; k < iters; ++k) {
        float4 pa = p4[i];
        float4 ta = t4[i];
        float4 pb = p4[i + stride];
        float4 tb = t4[i + stride];
        float4 pc = p4[i + 2 * stride];
        float4 tc = t4[i + 2 * stride];
        float4 pd = p4[i + 3 * stride];
        float4 td = t4[i + 3 * stride];
        acc0 += WMSE4(pa, ta);
        acc1 += WMSE4(pb, tb);
        acc2 += WMSE4(pc, tc);
        acc3 += WMSE4(pd, td);
        i += 4 * stride;
    }
    float acc = (acc0 + acc1) + (acc2 + acc3);

    // float4 remainder (none at this N, kept for generality)
    for (long long j = n4_main + tid; j < n4; j += stride) {
        float4 p = p4[j];
        float4 t = t4[j];
        acc += WMSE4(p, t);
    }
    // scalar tail (N not multiple of 4)
    for (long long j = (n4 << 2) + tid; j < n; j += stride) {
        acc += wmse_elem(pred[j], targ[j], e0, e1, e2, e3, e4, e5, w0, w1, w2, w3, w4);
    }

    // wave64 reduce
    #pragma unroll
    for (int off = 32; off > 0; off >>= 1)
        acc += __shfl_down(acc, off, 64);

    __shared__ float smem[4];  // 256 threads = 4 waves
    const int lane = threadIdx.x & 63;
    const int wid = threadIdx.x >> 6;
    if (lane == 0) smem[wid] = acc;
    __syncthreads();
    if (threadIdx.x == 0) {
        // one plain store per block -- no atomic contention
        partial[blockIdx.x] = smem[0] + smem[1] + smem[2] + smem[3];
    }
}

__global__ __launch_bounds__(256) void wmse_reduce_kernel(
    const float* __restrict__ partial, int nparts,
    const float* __restrict__ weights, float* __restrict__ out) {
    const float wsum = weights[0] + weights[1] + weights[2] + weights[3] + weights[4];

    float acc = 0.0f;
    for (int i = threadIdx.x; i < nparts; i += blockDim.x)
        acc += partial[i];

    #pragma unroll
    for (int off = 32; off > 0; off >>= 1)
        acc += __shfl_down(acc, off, 64);

    __shared__ float smem[4];
    const int lane = threadIdx.x & 63;
    const int wid = threadIdx.x >> 6;
    if (lane == 0) smem[wid] = acc;
    __syncthreads();
    if (threadIdx.x == 0)
        out[0] = (smem[0] + smem[1] + smem[2] + smem[3]) / wsum;
}

extern "C" void kernel_launch(void* const* d_in, const int* in_sizes, int n_in,
                              void* d_out, int out_size, void* d_ws, size_t ws_size,
                              hipStream_t stream) {
    const float* pred    = (const float*)d_in[0];
    const float* targ    = (const float*)d_in[1];
    const float* weights = (const float*)d_in[2];
    const float* edge    = (const float*)d_in[3];
    float* out = (float*)d_out;
    float* partial = (float*)d_ws;    // 2048 floats = 8 KB scratch
    const long long n = (long long)in_sizes[0];

    const int block = 256;
    const int grid = 2048;   // 8 blocks/CU
    WeightedMSELoss_60335700574782_kernel<<<grid, block, 0, stream>>>(
        pred, targ, edge, weights, partial, n);
    wmse_reduce_kernel<<<1, block, 0, stream>>>(partial, grid, weights, out);
}

// Round 6
// 272.758 us; speedup vs baseline: 1.0538x; 1.0538x over previous
//
#include <hip/hip_runtime.h>

// Weighted MSE loss:
//   bin i s.t. edge[i] < t <= edge[i+1]  -> weight[i]; outside -> 0
//   loss = sum(w * (p - t)^2) / sum(weights)
// R5: flat massive-grid structure (copy-mimic). R1/R2/R4 all ~110-120us at
// only 2.2 TB/s effective regardless of ILP or atomics -> suspect the
// 2048-block grid-stride loop (8-32MB jumps, long-lived waves) vs the
// proven-fast flat kernels (m13 copy 6.29 TB/s). Here: 32768 blocks, each
// block = one contiguous 4KB window per array, 1 float4/thread/array, no
// loops; block sum -> hashed atomicAdd into 2048 slots (8KB ws); 1-block
// finish kernel scales by 1/sum(w).

#define NSLOTS 2048

__global__ void wmse_zero_ws(float* __restrict__ ws) {
    ws[blockIdx.x * blockDim.x + threadIdx.x] = 0.0f;   // 8 x 256 = 2048
}

__device__ __forceinline__ float wmse_elem(float p, float t,
                                           float e0, float e1, float e2,
                                           float e3, float e4, float e5,
                                           float w0, float w1, float w2,
                                           float w3, float w4) {
    float w = 0.0f;
    w = (t > e0 && t <= e1) ? w0 : w;
    w = (t > e1 && t <= e2) ? w1 : w;
    w = (t > e2 && t <= e3) ? w2 : w;
    w = (t > e3 && t <= e4) ? w3 : w;
    w = (t > e4 && t <= e5) ? w4 : w;
    float d = p - t;
    return w * d * d;
}

__global__ __launch_bounds__(256) void WeightedMSELoss_60335700574782_kernel(
    const float* __restrict__ pred, const float* __restrict__ targ,
    const float* __restrict__ edge, const float* __restrict__ weights,
    float* __restrict__ partial, long long n4) {
    const float e0 = edge[0], e1 = edge[1], e2 = edge[2];
    const float e3 = edge[3], e4 = edge[4], e5 = edge[5];
    const float w0 = weights[0], w1 = weights[1], w2 = weights[2];
    const float w3 = weights[3], w4 = weights[4];

    const long long i = (long long)blockIdx.x * blockDim.x + threadIdx.x;
    const float4* __restrict__ p4 = (const float4*)pred;
    const float4* __restrict__ t4 = (const float4*)targ;

    float acc = 0.0f;
    if (i < n4) {
        float4 p = p4[i];
        float4 t = t4[i];
        acc  = wmse_elem(p.x, t.x, e0, e1, e2, e3, e4, e5, w0, w1, w2, w3, w4);
        acc += wmse_elem(p.y, t.y, e0, e1, e2, e3, e4, e5, w0, w1, w2, w3, w4);
        acc += wmse_elem(p.z, t.z, e0, e1, e2, e3, e4, e5, w0, w1, w2, w3, w4);
        acc += wmse_elem(p.w, t.w, e0, e1, e2, e3, e4, e5, w0, w1, w2, w3, w4);
    }

    // wave64 reduce
    #pragma unroll
    for (int off = 32; off > 0; off >>= 1)
        acc += __shfl_down(acc, off, 64);

    __shared__ float smem[4];  // 256 threads = 4 waves
    const int lane = threadIdx.x & 63;
    const int wid = threadIdx.x >> 6;
    if (lane == 0) smem[wid] = acc;
    __syncthreads();
    if (threadIdx.x == 0) {
        float bsum = smem[0] + smem[1] + smem[2] + smem[3];
        // hashed slots: blocks sharing a slot are dispatched ~2048 apart
        atomicAdd(&partial[blockIdx.x & (NSLOTS - 1)], bsum);
    }
}

__global__ __launch_bounds__(256) void wmse_finish_kernel(
    const float* __restrict__ partial,
    const float* __restrict__ pred, const float* __restrict__ targ,
    const float* __restrict__ edge, const float* __restrict__ weights,
    float* __restrict__ out, long long n) {
    const float e0 = edge[0], e1 = edge[1], e2 = edge[2];
    const float e3 = edge[3], e4 = edge[4], e5 = edge[5];
    const float w0 = weights[0], w1 = weights[1], w2 = weights[2];
    const float w3 = weights[3], w4 = weights[4];
    const float inv_wsum = 1.0f / (w0 + w1 + w2 + w3 + w4);

    float acc = 0.0f;
    for (int i = threadIdx.x; i < NSLOTS; i += blockDim.x)
        acc += partial[i];

    // scalar tail for n % 4 != 0 (none at this N)
    const long long n4 = n >> 2;
    for (long long j = (n4 << 2) + threadIdx.x; j < n; j += blockDim.x)
        acc += wmse_elem(pred[j], targ[j], e0, e1, e2, e3, e4, e5, w0, w1, w2, w3, w4);

    #pragma unroll
    for (int off = 32; off > 0; off >>= 1)
        acc += __shfl_down(acc, off, 64);

    __shared__ float smem[4];
    const int lane = threadIdx.x & 63;
    const int wid = threadIdx.x >> 6;
    if (lane == 0) smem[wid] = acc;
    __syncthreads();
    if (threadIdx.x == 0)
        out[0] = (smem[0] + smem[1] + smem[2] + smem[3]) * inv_wsum;
}

extern "C" void kernel_launch(void* const* d_in, const int* in_sizes, int n_in,
                              void* d_out, int out_size, void* d_ws, size_t ws_size,
                              hipStream_t stream) {
    const float* pred    = (const float*)d_in[0];
    const float* targ    = (const float*)d_in[1];
    const float* weights = (const float*)d_in[2];
    const float* edge    = (const float*)d_in[3];
    float* out = (float*)d_out;
    float* partial = (float*)d_ws;    // NSLOTS floats = 8 KB scratch (poisoned -> zero)
    const long long n = (long long)in_sizes[0];
    const long long n4 = n >> 2;

    wmse_zero_ws<<<NSLOTS / 256, 256, 0, stream>>>(partial);

    const int block = 256;
    const int grid = (int)((n4 + block - 1) / block);   // 32768 flat blocks
    WeightedMSELoss_60335700574782_kernel<<<grid, block, 0, stream>>>(
        pred, targ, edge, weights, partial, n4);

    wmse_finish_kernel<<<1, block, 0, stream>>>(
        partial, pred, targ, edge, weights, out, n);
}